// Round 4
// baseline (5216.328 us; speedup 1.0000x reference)
//
#include <hip/hip_runtime.h>

#define N_USERS 100000
#define N_ITEMS 50000
#define N_NODES 150000
#define EMBED 64
#define N_LAYERS 3

#define BSH 7                    // log2(rows per bucket)
#define BR 128                   // rows per bucket
#define NB ((N_NODES + BR - 1) / BR)     // 1172 buckets
#define CAP 4608                 // edge capacity per bucket (mean 4096, +8 sigma)
#define PCHUNK 8192              // edges per partition workgroup

// ---------------------------------------------------------------------------
// init: ego0 = concat(u_emb + u_emb_pre, i_emb + i_emb_pre); acc = ego0
// ---------------------------------------------------------------------------
__global__ void lgcn_init(const float* __restrict__ u, const float* __restrict__ it,
                          const float* __restrict__ up, const float* __restrict__ ip,
                          float* __restrict__ ego, float* __restrict__ acc) {
    int idx = blockIdx.x * blockDim.x + threadIdx.x;  // float4 index
    const int total = N_NODES * EMBED / 4;
    if (idx >= total) return;
    const int uCount = N_USERS * EMBED / 4;
    float4 v;
    if (idx < uCount) {
        float4 a = reinterpret_cast<const float4*>(u)[idx];
        float4 b = reinterpret_cast<const float4*>(up)[idx];
        v = make_float4(a.x + b.x, a.y + b.y, a.z + b.z, a.w + b.w);
    } else {
        int j = idx - uCount;
        float4 a = reinterpret_cast<const float4*>(it)[j];
        float4 b = reinterpret_cast<const float4*>(ip)[j];
        v = make_float4(a.x + b.x, a.y + b.y, a.z + b.z, a.w + b.w);
    }
    reinterpret_cast<float4*>(ego)[idx] = v;
    reinterpret_cast<float4*>(acc)[idx] = v;
}

// ---------------------------------------------------------------------------
// cursor init: fill[b] = b * CAP
// ---------------------------------------------------------------------------
__global__ void lgcn_fill_init(int* __restrict__ fill) {
    int b = blockIdx.x * blockDim.x + threadIdx.x;
    if (b < NB) fill[b] = b * CAP;
}

// ---------------------------------------------------------------------------
// partition: scatter edges into fixed-capacity bucket regions of bcv,
// packed as int2{ (rowLocal<<18)|col , bits(val) }.
// LDS histogram -> one global cursor reservation per bucket per WG.
// ---------------------------------------------------------------------------
__global__ __launch_bounds__(512) void lgcn_partition(
        const int* __restrict__ rows, const int* __restrict__ cols,
        const float* __restrict__ vals, int* __restrict__ fill,
        int2* __restrict__ bcv, int nnz) {
    __shared__ int lcnt[NB];
    __shared__ int lbase[NB];
    int c0 = blockIdx.x * PCHUNK;
    int cend = min(c0 + PCHUNK, nnz);
    for (int b = threadIdx.x; b < NB; b += 512) lcnt[b] = 0;
    __syncthreads();
    for (int e = c0 + threadIdx.x; e < cend; e += 512)
        atomicAdd(&lcnt[rows[e] >> BSH], 1);
    __syncthreads();
    for (int b = threadIdx.x; b < NB; b += 512) {
        int c = lcnt[b];
        lbase[b] = c ? atomicAdd(&fill[b], c) : 0;
        lcnt[b] = 0;  // reuse as intra-WG cursor
    }
    __syncthreads();
    const int maxPos = NB * CAP - 1;
    for (int e = c0 + threadIdx.x; e < cend; e += 512) {
        int r = rows[e];
        int b = r >> BSH;
        int pos = lbase[b] + atomicAdd(&lcnt[b], 1);
        pos = min(pos, maxPos);  // memory-safety clamp (never hit at CAP margin)
        bcv[pos] = make_int2(((r & (BR - 1)) << 18) | cols[e], __float_as_int(vals[e]));
    }
}

// ---------------------------------------------------------------------------
// SpMM via LDS accumulation: one WG (512 thr) per 128-row bucket.
// Each wave takes a contiguous sub-range of the bucket's edges; all 64 lanes
// share the edge (scalar load), gather x[col][lane], atomicAdd into LDS.
// Flush fuses ego write + acc update (+ final scale).
// ---------------------------------------------------------------------------
template <bool WRITE_EGO>
__global__ __launch_bounds__(512, 8) void lgcn_spmm_lds(
        const int* __restrict__ fill, const int2* __restrict__ bcv,
        const float* __restrict__ x, float* __restrict__ ego_out,
        float* __restrict__ acc, float scale) {
    __shared__ float sm[BR * EMBED];  // 32 KB
    int b = blockIdx.x;
    int beg = b * CAP;
    int end = fill[b];

    float4* sm4 = reinterpret_cast<float4*>(sm);
    for (int i = threadIdx.x; i < BR * EMBED / 4; i += 512)
        sm4[i] = make_float4(0.f, 0.f, 0.f, 0.f);
    __syncthreads();

    int wid = threadIdx.x >> 6;
    int lane = threadIdx.x & 63;
    int cnt = end - beg;
    int per = (cnt + 7) >> 3;  // edges per wave (8 waves)
    int ws = beg + wid * per;
    int we = min(ws + per, end);

    int e = ws;
    for (; e + 2 <= we; e += 2) {
        int e0 = __builtin_amdgcn_readfirstlane(e);
        int2 p0 = bcv[e0];
        int2 p1 = bcv[e0 + 1];
        float xv0 = x[(size_t)(p0.x & 0x3FFFF) * EMBED + lane];
        float xv1 = x[(size_t)(p1.x & 0x3FFFF) * EMBED + lane];
        atomicAdd(&sm[((p0.x >> 18) << 6) + lane], __int_as_float(p0.y) * xv0);
        atomicAdd(&sm[((p1.x >> 18) << 6) + lane], __int_as_float(p1.y) * xv1);
    }
    if (e < we) {
        int e0 = __builtin_amdgcn_readfirstlane(e);
        int2 p0 = bcv[e0];
        float xv0 = x[(size_t)(p0.x & 0x3FFFF) * EMBED + lane];
        atomicAdd(&sm[((p0.x >> 18) << 6) + lane], __int_as_float(p0.y) * xv0);
    }
    __syncthreads();

    // flush: 128 rows * 16 float4 = 2048 float4 per bucket
    const int out4 = BR * EMBED / 4;
    size_t base4 = (size_t)b * out4;
    const size_t lim4 = (size_t)N_NODES * EMBED / 4;
    float4* acc4 = reinterpret_cast<float4*>(acc);
    float4* ego4 = reinterpret_cast<float4*>(ego_out);
    for (int i = threadIdx.x; i < out4; i += 512) {
        size_t o = base4 + i;
        if (o < lim4) {
            float4 s = sm4[i];
            if (WRITE_EGO) ego4[o] = s;
            float4 a = acc4[o];
            a.x = (a.x + s.x) * scale;
            a.y = (a.y + s.y) * scale;
            a.z = (a.z + s.z) * scale;
            a.w = (a.w + s.w) * scale;
            acc4[o] = a;
        }
    }
}

extern "C" void kernel_launch(void* const* d_in, const int* in_sizes, int n_in,
                              void* d_out, int out_size, void* d_ws, size_t ws_size,
                              hipStream_t stream) {
    const int*   rows = (const int*)d_in[0];
    const int*   cols = (const int*)d_in[1];
    const float* vals = (const float*)d_in[2];
    const float* u    = (const float*)d_in[3];
    const float* it   = (const float*)d_in[4];
    const float* up   = (const float*)d_in[5];
    const float* ip   = (const float*)d_in[6];
    const int nnz = in_sizes[0];

    float* acc = (float*)d_out;

    // workspace layout
    float* ego0 = (float*)d_ws;                                // 38.4 MB
    float* ego1 = ego0 + (size_t)N_NODES * EMBED;              // 38.4 MB
    int2*  bcv  = (int2*)(ego1 + (size_t)N_NODES * EMBED);     // NB*CAP*8 = 43.2 MB
    int*   fill = (int*)(bcv + (size_t)NB * CAP);              // NB ints

    const int tpb = 256;
    const int totalVec = N_NODES * EMBED / 4;

    lgcn_init<<<(totalVec + tpb - 1) / tpb, tpb, 0, stream>>>(u, it, up, ip, ego0, acc);
    lgcn_fill_init<<<(NB + tpb - 1) / tpb, tpb, 0, stream>>>(fill);
    lgcn_partition<<<(nnz + PCHUNK - 1) / PCHUNK, 512, 0, stream>>>(
        rows, cols, vals, fill, bcv, nnz);

    lgcn_spmm_lds<true><<<NB, 512, 0, stream>>>(fill, bcv, ego0, ego1, acc, 1.0f);
    lgcn_spmm_lds<true><<<NB, 512, 0, stream>>>(fill, bcv, ego1, ego0, acc, 1.0f);
    lgcn_spmm_lds<false><<<NB, 512, 0, stream>>>(fill, bcv, ego0, nullptr, acc,
                                                 1.0f / (N_LAYERS + 1));
}

// Round 5
// 1035.210 us; speedup vs baseline: 5.0389x; 5.0389x over previous
//
#include <hip/hip_runtime.h>

#define N_USERS 100000
#define N_ITEMS 50000
#define N_NODES 150000
#define EMBED 64
#define N_LAYERS 3

#define BUCKET_SHIFT 10
#define BUCKET_ROWS 1024
#define N_BUCKETS ((N_NODES + BUCKET_ROWS - 1) / BUCKET_ROWS)   // 147
#define PASSA_CHUNK 4096

// ---------------------------------------------------------------------------
// init: ego0 = concat(u_emb + u_emb_pre, i_emb + i_emb_pre); acc = ego0
// ---------------------------------------------------------------------------
__global__ void lgcn_init(const float* __restrict__ u, const float* __restrict__ it,
                          const float* __restrict__ up, const float* __restrict__ ip,
                          float* __restrict__ ego, float* __restrict__ acc) {
    int idx = blockIdx.x * blockDim.x + threadIdx.x;  // float4 index
    const int total = N_NODES * EMBED / 4;
    if (idx >= total) return;
    const int uCount = N_USERS * EMBED / 4;
    float4 v;
    if (idx < uCount) {
        float4 a = reinterpret_cast<const float4*>(u)[idx];
        float4 b = reinterpret_cast<const float4*>(up)[idx];
        v = make_float4(a.x + b.x, a.y + b.y, a.z + b.z, a.w + b.w);
    } else {
        int j = idx - uCount;
        float4 a = reinterpret_cast<const float4*>(it)[j];
        float4 b = reinterpret_cast<const float4*>(ip)[j];
        v = make_float4(a.x + b.x, a.y + b.y, a.z + b.z, a.w + b.w);
    }
    reinterpret_cast<float4*>(ego)[idx] = v;
    reinterpret_cast<float4*>(acc)[idx] = v;
}

// ---------------------------------------------------------------------------
// row histogram
// ---------------------------------------------------------------------------
__global__ void lgcn_hist(const int* __restrict__ rows, int* __restrict__ counts, int nnz) {
    int e = blockIdx.x * blockDim.x + threadIdx.x;
    if (e < nnz) atomicAdd(&counts[rows[e]], 1);
}

// ---------------------------------------------------------------------------
// bucket counts = reduction of row counts over each 1024-row bucket
// ---------------------------------------------------------------------------
__global__ void lgcn_bucket_cnt(const int* __restrict__ counts, int* __restrict__ bucketCnt) {
    __shared__ int sm[256];
    int b = blockIdx.x;
    int base = b * BUCKET_ROWS;
    int s = 0;
    for (int i = threadIdx.x; i < BUCKET_ROWS; i += 256) {
        int idx = base + i;
        if (idx < N_NODES) s += counts[idx];
    }
    sm[threadIdx.x] = s;
    __syncthreads();
    for (int off = 128; off > 0; off >>= 1) {
        if (threadIdx.x < (unsigned)off) sm[threadIdx.x] += sm[threadIdx.x + off];
        __syncthreads();
    }
    if (threadIdx.x == 0) bucketCnt[b] = sm[0];
}

// ---------------------------------------------------------------------------
// exclusive scan of bucket counts (N_BUCKETS <= 256), one block
// ---------------------------------------------------------------------------
__global__ void lgcn_bucket_scan(const int* __restrict__ bucketCnt, int* __restrict__ bucketBase,
                                 int* __restrict__ bucketFill, int* __restrict__ rowptr) {
    __shared__ int sm[256];
    int c = (threadIdx.x < N_BUCKETS) ? bucketCnt[threadIdx.x] : 0;
    sm[threadIdx.x] = c;
    __syncthreads();
    for (int off = 1; off < 256; off <<= 1) {
        int t = (threadIdx.x >= (unsigned)off) ? sm[threadIdx.x - off] : 0;
        __syncthreads();
        sm[threadIdx.x] += t;
        __syncthreads();
    }
    int excl = sm[threadIdx.x] - c;
    if (threadIdx.x < N_BUCKETS) { bucketBase[threadIdx.x] = excl; bucketFill[threadIdx.x] = excl; }
    if (threadIdx.x == N_BUCKETS - 1) rowptr[N_NODES] = sm[threadIdx.x];
}

// ---------------------------------------------------------------------------
// per-bucket row scan: rowptr[i] = bucketBase[b] + exclusive_scan(counts within bucket)
// ---------------------------------------------------------------------------
__global__ void lgcn_row_scan(const int* __restrict__ counts, const int* __restrict__ bucketBase,
                              int* __restrict__ rowptr, int* __restrict__ fill) {
    __shared__ int sm[BUCKET_ROWS];
    int b = blockIdx.x;
    int i = b * BUCKET_ROWS + threadIdx.x;
    int c = (i < N_NODES) ? counts[i] : 0;
    sm[threadIdx.x] = c;
    __syncthreads();
    for (int off = 1; off < BUCKET_ROWS; off <<= 1) {
        int t = (threadIdx.x >= (unsigned)off) ? sm[threadIdx.x - off] : 0;
        __syncthreads();
        sm[threadIdx.x] += t;
        __syncthreads();
    }
    if (i < N_NODES) {
        int v = bucketBase[b] + sm[threadIdx.x] - c;
        rowptr[i] = v;
        fill[i] = v;
    }
}

// ---------------------------------------------------------------------------
// Pass A: partition edges into bucket-contiguous streams:
//   br[pos] = row,  pcv[pos] = int2(col, bits(val))
// ---------------------------------------------------------------------------
__global__ void lgcn_partition(const int* __restrict__ rows, const int* __restrict__ cols,
                               const float* __restrict__ vals, int* __restrict__ bucketFill,
                               int* __restrict__ br, int2* __restrict__ pcv, int nnz) {
    __shared__ int lcnt[N_BUCKETS];
    __shared__ int lbase[N_BUCKETS];
    int chunk0 = blockIdx.x * PASSA_CHUNK;
    for (int b = threadIdx.x; b < N_BUCKETS; b += blockDim.x) lcnt[b] = 0;
    __syncthreads();
    int end = min(chunk0 + PASSA_CHUNK, nnz);
    for (int e = chunk0 + threadIdx.x; e < end; e += blockDim.x) {
        int r = rows[e];
        atomicAdd(&lcnt[r >> BUCKET_SHIFT], 1);
    }
    __syncthreads();
    for (int b = threadIdx.x; b < N_BUCKETS; b += blockDim.x) {
        int c = lcnt[b];
        lbase[b] = c ? atomicAdd(&bucketFill[b], c) : 0;
        lcnt[b] = 0;  // reuse as intra-WG cursor
    }
    __syncthreads();
    for (int e = chunk0 + threadIdx.x; e < end; e += blockDim.x) {
        int r = rows[e];
        int b = r >> BUCKET_SHIFT;
        int pos = lbase[b] + atomicAdd(&lcnt[b], 1);
        br[pos] = r;
        pcv[pos] = make_int2(cols[e], __float_as_int(vals[e]));
    }
}

// ---------------------------------------------------------------------------
// Pass B: scatter (col,val) to exact row-sorted position. Input is
// bucket-sorted, so concurrent writes stay within a few buckets' windows.
// ---------------------------------------------------------------------------
__global__ void lgcn_scatter_cv(const int* __restrict__ br, const int2* __restrict__ pcv,
                                int* __restrict__ fill, int2* __restrict__ cv, int nnz) {
    int e = blockIdx.x * blockDim.x + threadIdx.x;
    if (e >= nnz) return;
    int r = br[e];
    int pos = atomicAdd(&fill[r], 1);
    cv[pos] = pcv[e];
}

// ---------------------------------------------------------------------------
// CSR SpMM, one wave per row, lane = dim. Fused acc update (+ final scale).
// Predicated unroll-8: all chunks are full 8 loads (tail indices clamped to
// the last edge, their val zeroed) -> 8 gathers in flight per waitcnt.
// ---------------------------------------------------------------------------
template <bool WRITE_EGO>
__global__ void lgcn_spmm_csr(const int* __restrict__ rowptr, const int2* __restrict__ cv,
                              const float* __restrict__ x, float* __restrict__ ego_out,
                              float* __restrict__ acc, float scale) {
    int row = blockIdx.x * (blockDim.x >> 6) + (threadIdx.x >> 6);
    row = __builtin_amdgcn_readfirstlane(row);   // wave-uniform -> scalar loads
    if (row >= N_NODES) return;
    int lane = threadIdx.x & 63;
    int beg = rowptr[row];
    int end = rowptr[row + 1];
    float s = 0.f;
    int lim = end - 1;
    for (int e = beg; e < end; e += 8) {
        int2 p0 = cv[min(e + 0, lim)];
        int2 p1 = cv[min(e + 1, lim)];
        int2 p2 = cv[min(e + 2, lim)];
        int2 p3 = cv[min(e + 3, lim)];
        int2 p4 = cv[min(e + 4, lim)];
        int2 p5 = cv[min(e + 5, lim)];
        int2 p6 = cv[min(e + 6, lim)];
        int2 p7 = cv[min(e + 7, lim)];
        float x0 = x[(size_t)p0.x * EMBED + lane];
        float x1 = x[(size_t)p1.x * EMBED + lane];
        float x2 = x[(size_t)p2.x * EMBED + lane];
        float x3 = x[(size_t)p3.x * EMBED + lane];
        float x4 = x[(size_t)p4.x * EMBED + lane];
        float x5 = x[(size_t)p5.x * EMBED + lane];
        float x6 = x[(size_t)p6.x * EMBED + lane];
        float x7 = x[(size_t)p7.x * EMBED + lane];
        float v0 = (e + 0 <= lim) ? __int_as_float(p0.y) : 0.f;
        float v1 = (e + 1 <= lim) ? __int_as_float(p1.y) : 0.f;
        float v2 = (e + 2 <= lim) ? __int_as_float(p2.y) : 0.f;
        float v3 = (e + 3 <= lim) ? __int_as_float(p3.y) : 0.f;
        float v4 = (e + 4 <= lim) ? __int_as_float(p4.y) : 0.f;
        float v5 = (e + 5 <= lim) ? __int_as_float(p5.y) : 0.f;
        float v6 = (e + 6 <= lim) ? __int_as_float(p6.y) : 0.f;
        float v7 = (e + 7 <= lim) ? __int_as_float(p7.y) : 0.f;
        s += v0 * x0; s += v1 * x1; s += v2 * x2; s += v3 * x3;
        s += v4 * x4; s += v5 * x5; s += v6 * x6; s += v7 * x7;
    }
    size_t o = (size_t)row * EMBED + lane;
    if (WRITE_EGO) ego_out[o] = s;
    acc[o] = (acc[o] + s) * scale;
}

extern "C" void kernel_launch(void* const* d_in, const int* in_sizes, int n_in,
                              void* d_out, int out_size, void* d_ws, size_t ws_size,
                              hipStream_t stream) {
    const int*   rows = (const int*)d_in[0];
    const int*   cols = (const int*)d_in[1];
    const float* vals = (const float*)d_in[2];
    const float* u    = (const float*)d_in[3];
    const float* it   = (const float*)d_in[4];
    const float* up   = (const float*)d_in[5];
    const float* ip   = (const float*)d_in[6];
    const int nnz = in_sizes[0];

    float* acc = (float*)d_out;

    // workspace layout
    float* ego0       = (float*)d_ws;                              // 38.4 MB
    float* ego1       = ego0 + (size_t)N_NODES * EMBED;            // 38.4 MB
    int*   counts     = (int*)(ego1 + (size_t)N_NODES * EMBED);    // 0.6 MB
    int*   fill       = counts + N_NODES;                          // 0.6 MB
    int*   rowptr     = fill + N_NODES;                            // N_NODES+1
    int*   bucketCnt  = rowptr + N_NODES + 1;                      // 147
    int*   bucketBase = bucketCnt + N_BUCKETS;                     // 147
    int*   bucketFill = bucketBase + N_BUCKETS;                    // 147
    int*   pad        = bucketFill + N_BUCKETS;
    size_t off        = ((size_t)(pad - (int*)d_ws) + 3) & ~(size_t)3;  // 16B align
    int2*  cv         = (int2*)((int*)d_ws + off);                 // 38.4 MB
    int2*  pcv        = cv + nnz;                                  // 38.4 MB
    int*   br         = (int*)(pcv + nnz);                         // 19.2 MB

    const int tpb = 256;
    const int totalVec = N_NODES * EMBED / 4;

    lgcn_init<<<(totalVec + tpb - 1) / tpb, tpb, 0, stream>>>(u, it, up, ip, ego0, acc);

    hipMemsetAsync(counts, 0, N_NODES * sizeof(int), stream);
    lgcn_hist<<<(nnz + tpb - 1) / tpb, tpb, 0, stream>>>(rows, counts, nnz);
    lgcn_bucket_cnt<<<N_BUCKETS, 256, 0, stream>>>(counts, bucketCnt);
    lgcn_bucket_scan<<<1, 256, 0, stream>>>(bucketCnt, bucketBase, bucketFill, rowptr);
    lgcn_row_scan<<<N_BUCKETS, BUCKET_ROWS, 0, stream>>>(counts, bucketBase, rowptr, fill);
    lgcn_partition<<<(nnz + PASSA_CHUNK - 1) / PASSA_CHUNK, tpb, 0, stream>>>(
        rows, cols, vals, bucketFill, br, pcv, nnz);
    lgcn_scatter_cv<<<(nnz + tpb - 1) / tpb, tpb, 0, stream>>>(br, pcv, fill, cv, nnz);

    const int rowsPerBlock = tpb / 64;
    const int spmmBlocks = (N_NODES + rowsPerBlock - 1) / rowsPerBlock;

    lgcn_spmm_csr<true><<<spmmBlocks, tpb, 0, stream>>>(rowptr, cv, ego0, ego1, acc, 1.0f);
    lgcn_spmm_csr<true><<<spmmBlocks, tpb, 0, stream>>>(rowptr, cv, ego1, ego0, acc, 1.0f);
    lgcn_spmm_csr<false><<<spmmBlocks, tpb, 0, stream>>>(rowptr, cv, ego0, nullptr, acc,
                                                         1.0f / (N_LAYERS + 1));
}

// Round 6
// 713.225 us; speedup vs baseline: 7.3137x; 1.4515x over previous
//
#include <hip/hip_runtime.h>

#define N_USERS 100000
#define N_ITEMS 50000
#define N_NODES 150000
#define EMBED 64
#define N_LAYERS 3

#define BSH 8                                   // log2(rows per bucket)
#define BROWS 256                               // rows per bucket
#define NB ((N_NODES + BROWS - 1) / BROWS)      // 586 buckets
#define CAP 9216                                // mean 8192 + ~11 sigma
#define PCHUNK 4096                             // edges per partition WG
#define COLMASK 0x3FFFF                         // 18 bits for col (N_NODES<2^18)

// ---------------------------------------------------------------------------
// init: ego0 = concat(u_emb + u_emb_pre, i_emb + i_emb_pre); acc = ego0
// ---------------------------------------------------------------------------
__global__ void lgcn_init(const float* __restrict__ u, const float* __restrict__ it,
                          const float* __restrict__ up, const float* __restrict__ ip,
                          float* __restrict__ ego, float* __restrict__ acc) {
    int idx = blockIdx.x * blockDim.x + threadIdx.x;  // float4 index
    const int total = N_NODES * EMBED / 4;
    if (idx >= total) return;
    const int uCount = N_USERS * EMBED / 4;
    float4 v;
    if (idx < uCount) {
        float4 a = reinterpret_cast<const float4*>(u)[idx];
        float4 b = reinterpret_cast<const float4*>(up)[idx];
        v = make_float4(a.x + b.x, a.y + b.y, a.z + b.z, a.w + b.w);
    } else {
        int j = idx - uCount;
        float4 a = reinterpret_cast<const float4*>(it)[j];
        float4 b = reinterpret_cast<const float4*>(ip)[j];
        v = make_float4(a.x + b.x, a.y + b.y, a.z + b.z, a.w + b.w);
    }
    reinterpret_cast<float4*>(ego)[idx] = v;
    reinterpret_cast<float4*>(acc)[idx] = v;
}

// ---------------------------------------------------------------------------
// cursor init: fill[b] = b * CAP
// ---------------------------------------------------------------------------
__global__ void lgcn_fill_init(int* __restrict__ fill) {
    int b = blockIdx.x * blockDim.x + threadIdx.x;
    if (b < NB) fill[b] = b * CAP;
}

// ---------------------------------------------------------------------------
// partition: scatter edges into fixed-capacity bucket regions of pcvp,
// packed int2{ (rowLocal<<18)|col , bits(val) }.
// LDS chunk-histogram -> one global cursor reservation per bucket per WG.
// ---------------------------------------------------------------------------
__global__ void lgcn_partition(const int* __restrict__ rows, const int* __restrict__ cols,
                               const float* __restrict__ vals, int* __restrict__ fill,
                               int2* __restrict__ pcvp, int nnz) {
    __shared__ int lcnt[NB];
    __shared__ int lbase[NB];
    int c0 = blockIdx.x * PCHUNK;
    int cend = min(c0 + PCHUNK, nnz);
    for (int b = threadIdx.x; b < NB; b += blockDim.x) lcnt[b] = 0;
    __syncthreads();
    for (int e = c0 + threadIdx.x; e < cend; e += blockDim.x)
        atomicAdd(&lcnt[rows[e] >> BSH], 1);
    __syncthreads();
    for (int b = threadIdx.x; b < NB; b += blockDim.x) {
        int c = lcnt[b];
        lbase[b] = c ? atomicAdd(&fill[b], c) : 0;
        lcnt[b] = 0;  // reuse as intra-WG cursor
    }
    __syncthreads();
    for (int e = c0 + threadIdx.x; e < cend; e += blockDim.x) {
        int r = rows[e];
        int b = r >> BSH;
        int pos = lbase[b] + atomicAdd(&lcnt[b], 1);
        pos = min(pos, (b + 1) * CAP - 1);  // memory-safety clamp (never hit)
        pcvp[pos] = make_int2(((r & (BROWS - 1)) << 18) | cols[e], __float_as_int(vals[e]));
    }
}

// ---------------------------------------------------------------------------
// ebase: exclusive scan of realized bucket counts -> global edge base;
// also writes rowptr[N_NODES] = nnz. One block, 1024 threads (NB=586 fits).
// ---------------------------------------------------------------------------
__global__ __launch_bounds__(1024) void lgcn_ebase(const int* __restrict__ fill,
                                                   int* __restrict__ ebase,
                                                   int* __restrict__ rowptr, int nnz) {
    __shared__ int sm[1024];
    int c = (threadIdx.x < NB) ? (fill[threadIdx.x] - threadIdx.x * CAP) : 0;
    sm[threadIdx.x] = c;
    __syncthreads();
    for (int off = 1; off < 1024; off <<= 1) {
        int t = (threadIdx.x >= (unsigned)off) ? sm[threadIdx.x - off] : 0;
        __syncthreads();
        sm[threadIdx.x] += t;
        __syncthreads();
    }
    if (threadIdx.x < NB) ebase[threadIdx.x] = sm[threadIdx.x] - c;
    if (threadIdx.x == 0) rowptr[N_NODES] = nnz;
}

// ---------------------------------------------------------------------------
// bsort: one WG (256 thr) per 256-row bucket. LDS histogram of rowLocal,
// LDS scan -> rowptr + LDS cursors, then scatter (col,val) to exact
// row-sorted positions (64 KB L2-local window per WG).
// ---------------------------------------------------------------------------
__global__ __launch_bounds__(BROWS) void lgcn_bsort(const int2* __restrict__ pcvp,
                                                    const int* __restrict__ fill,
                                                    const int* __restrict__ ebase,
                                                    int* __restrict__ rowptr,
                                                    int2* __restrict__ cv) {
    __shared__ int sm[BROWS];
    __shared__ int cur[BROWS];
    int b = blockIdx.x;
    int beg = b * CAP;
    int end = min(fill[b], beg + CAP);
    sm[threadIdx.x] = 0;
    __syncthreads();
    for (int i = beg + threadIdx.x; i < end; i += BROWS)
        atomicAdd(&sm[((unsigned)pcvp[i].x) >> 18], 1);
    __syncthreads();
    int c = sm[threadIdx.x];
    for (int off = 1; off < BROWS; off <<= 1) {
        int t = (threadIdx.x >= (unsigned)off) ? sm[threadIdx.x - off] : 0;
        __syncthreads();
        sm[threadIdx.x] += t;
        __syncthreads();
    }
    int eb = ebase[b];
    int excl = sm[threadIdx.x] - c;
    cur[threadIdx.x] = eb + excl;
    int node = b * BROWS + (int)threadIdx.x;
    if (node < N_NODES) rowptr[node] = eb + excl;
    __syncthreads();
    for (int i = beg + threadIdx.x; i < end; i += BROWS) {
        int2 p = pcvp[i];
        int rl = ((unsigned)p.x) >> 18;
        int pos = atomicAdd(&cur[rl], 1);
        cv[pos] = make_int2(p.x & COLMASK, p.y);
    }
}

// ---------------------------------------------------------------------------
// CSR SpMM, one wave per row, lane = dim. Fused acc update (+ final scale).
// Predicated unroll-8 keeps 8 gathers in flight per waitcnt.
// ---------------------------------------------------------------------------
template <bool WRITE_EGO>
__global__ void lgcn_spmm_csr(const int* __restrict__ rowptr, const int2* __restrict__ cv,
                              const float* __restrict__ x, float* __restrict__ ego_out,
                              float* __restrict__ acc, float scale) {
    int row = blockIdx.x * (blockDim.x >> 6) + (threadIdx.x >> 6);
    row = __builtin_amdgcn_readfirstlane(row);   // wave-uniform -> scalar loads
    if (row >= N_NODES) return;
    int lane = threadIdx.x & 63;
    int beg = rowptr[row];
    int end = rowptr[row + 1];
    float s = 0.f;
    int lim = end - 1;
    for (int e = beg; e < end; e += 8) {
        int2 p0 = cv[min(e + 0, lim)];
        int2 p1 = cv[min(e + 1, lim)];
        int2 p2 = cv[min(e + 2, lim)];
        int2 p3 = cv[min(e + 3, lim)];
        int2 p4 = cv[min(e + 4, lim)];
        int2 p5 = cv[min(e + 5, lim)];
        int2 p6 = cv[min(e + 6, lim)];
        int2 p7 = cv[min(e + 7, lim)];
        float x0 = x[(size_t)p0.x * EMBED + lane];
        float x1 = x[(size_t)p1.x * EMBED + lane];
        float x2 = x[(size_t)p2.x * EMBED + lane];
        float x3 = x[(size_t)p3.x * EMBED + lane];
        float x4 = x[(size_t)p4.x * EMBED + lane];
        float x5 = x[(size_t)p5.x * EMBED + lane];
        float x6 = x[(size_t)p6.x * EMBED + lane];
        float x7 = x[(size_t)p7.x * EMBED + lane];
        float v0 = (e + 0 <= lim) ? __int_as_float(p0.y) : 0.f;
        float v1 = (e + 1 <= lim) ? __int_as_float(p1.y) : 0.f;
        float v2 = (e + 2 <= lim) ? __int_as_float(p2.y) : 0.f;
        float v3 = (e + 3 <= lim) ? __int_as_float(p3.y) : 0.f;
        float v4 = (e + 4 <= lim) ? __int_as_float(p4.y) : 0.f;
        float v5 = (e + 5 <= lim) ? __int_as_float(p5.y) : 0.f;
        float v6 = (e + 6 <= lim) ? __int_as_float(p6.y) : 0.f;
        float v7 = (e + 7 <= lim) ? __int_as_float(p7.y) : 0.f;
        s += v0 * x0; s += v1 * x1; s += v2 * x2; s += v3 * x3;
        s += v4 * x4; s += v5 * x5; s += v6 * x6; s += v7 * x7;
    }
    size_t o = (size_t)row * EMBED + lane;
    if (WRITE_EGO) ego_out[o] = s;
    acc[o] = (acc[o] + s) * scale;
}

extern "C" void kernel_launch(void* const* d_in, const int* in_sizes, int n_in,
                              void* d_out, int out_size, void* d_ws, size_t ws_size,
                              hipStream_t stream) {
    const int*   rows = (const int*)d_in[0];
    const int*   cols = (const int*)d_in[1];
    const float* vals = (const float*)d_in[2];
    const float* u    = (const float*)d_in[3];
    const float* it   = (const float*)d_in[4];
    const float* up   = (const float*)d_in[5];
    const float* ip   = (const float*)d_in[6];
    const int nnz = in_sizes[0];

    float* acc = (float*)d_out;

    // workspace layout (~159 MB)
    float* ego0   = (float*)d_ws;                               // 38.4 MB
    float* ego1   = ego0 + (size_t)N_NODES * EMBED;             // 38.4 MB
    int2*  cv     = (int2*)(ego1 + (size_t)N_NODES * EMBED);    // nnz*8 = 38.4 MB
    int2*  pcvp   = cv + nnz;                                   // NB*CAP*8 = 43.2 MB
    int*   fill   = (int*)(pcvp + (size_t)NB * CAP);            // NB
    int*   ebase  = fill + NB;                                  // NB
    int*   rowptr = ebase + NB;                                 // N_NODES+1

    const int tpb = 256;
    const int totalVec = N_NODES * EMBED / 4;

    lgcn_init<<<(totalVec + tpb - 1) / tpb, tpb, 0, stream>>>(u, it, up, ip, ego0, acc);
    lgcn_fill_init<<<(NB + tpb - 1) / tpb, tpb, 0, stream>>>(fill);
    lgcn_partition<<<(nnz + PCHUNK - 1) / PCHUNK, tpb, 0, stream>>>(
        rows, cols, vals, fill, pcvp, nnz);
    lgcn_ebase<<<1, 1024, 0, stream>>>(fill, ebase, rowptr, nnz);
    lgcn_bsort<<<NB, BROWS, 0, stream>>>(pcvp, fill, ebase, rowptr, cv);

    const int rowsPerBlock = tpb / 64;
    const int spmmBlocks = (N_NODES + rowsPerBlock - 1) / rowsPerBlock;

    lgcn_spmm_csr<true><<<spmmBlocks, tpb, 0, stream>>>(rowptr, cv, ego0, ego1, acc, 1.0f);
    lgcn_spmm_csr<true><<<spmmBlocks, tpb, 0, stream>>>(rowptr, cv, ego1, ego0, acc, 1.0f);
    lgcn_spmm_csr<false><<<spmmBlocks, tpb, 0, stream>>>(rowptr, cv, ego0, nullptr, acc,
                                                         1.0f / (N_LAYERS + 1));
}